// Round 7
// baseline (45.259 us; speedup 1.0000x reference)
//
#include <hip/hip_runtime.h>

// CapsuleLayer: u_hat[b,c,r,o] = sum_i W[c,r,o,i] * x[b,r,i]; out = squash(u_hat) over o.
// B=256, C=10, R=1152, I=8, O=16. fp32. Roofline: 188.7 MB write + ~15 MB fetch ≈ 30-32 us.
//
// R7 = R5 exactly (best so far, 39.3 us) with ONE change: nontemporal store -> plain store.
// Theory: nt bypasses L2 write-combining; plain stores let L2 absorb the 1 KB/wave
// full-line bursts and drain at the fill-kernel's 7 TB/s rate.

#define NB 256
#define NC 10
#define NR 1152
#define NI 8
#define NO 16
#define BPB 16            // batches per block
#define WPB 64            // (c,r) pairs per block

typedef float f32x4 __attribute__((ext_vector_type(4)));

template <int CTRL>
__device__ __forceinline__ float dpp_quad(float v) {
    int i = __builtin_bit_cast(int, v);
    int r = __builtin_amdgcn_update_dpp(i, i, CTRL, 0xF, 0xF, true);
    return __builtin_bit_cast(float, r);
}

__global__ __launch_bounds__(256, 5) void capsule_squash_kernel(
    const float* __restrict__ x,   // [B, R, I]
    const float* __restrict__ W,   // [C, R, O, I]
    float* __restrict__ out)       // [B, C, R, O]
{
    __shared__ float xs[BPB * WPB * NI];   // [16 b][64 r][8 i] = 32 KB

    const int tid = threadIdx.x;
    const int w0  = blockIdx.x * WPB;      // 64-aligned; 1152/64=18 so a block never crosses c
    const int r0  = w0 % NR;
    const int b0  = blockIdx.y * BPB;

    // ---- stage x[b0+0..15, r0+0..63, 0..7] -> LDS (8 dwordx4 per thread) ----
    {
        const int bi    = tid >> 4;        // b-slice 0..15
        const int chunk = tid & 15;        // float4 column 0..15
        const f32x4* src = reinterpret_cast<const f32x4*>(x + ((size_t)(b0 + bi) * NR + r0) * NI);
        f32x4* dst = reinterpret_cast<f32x4*>(xs + bi * (WPB * NI));
        #pragma unroll
        for (int k = 0; k < 8; ++k)
            dst[chunk + 16 * k] = src[chunk + 16 * k];
    }

    // ---- this lane's 4 W rows (8 float4 = 32 VGPR), overlapped with staging ----
    const int l4 = tid & 3;                // lane's o = l4*4 + 0..3
    const int g  = tid >> 2;               // group 0..63
    const int w  = w0 + g;
    const f32x4* wp = reinterpret_cast<const f32x4*>(W + (size_t)(w * NO + l4 * 4) * NI);
    f32x4 wr[8];
    #pragma unroll
    for (int k = 0; k < 8; ++k) wr[k] = wp[k];

    __syncthreads();

    f32x4* op = reinterpret_cast<f32x4*>(out + ((size_t)b0 * (NC * NR) + w) * NO + l4 * 4);
    const f32x4* xrow = reinterpret_cast<const f32x4*>(xs) + g * 2;

    #pragma unroll
    for (int j = 0; j < BPB; ++j) {
        const f32x4 x0 = xrow[j * (WPB * NI / 4)];
        const f32x4 x1 = xrow[j * (WPB * NI / 4) + 1];

        float u[4];
        #pragma unroll
        for (int k = 0; k < 4; ++k) {
            u[k] = wr[2*k].x   * x0.x + wr[2*k].y   * x0.y + wr[2*k].z   * x0.z + wr[2*k].w   * x0.w
                 + wr[2*k+1].x * x1.x + wr[2*k+1].y * x1.y + wr[2*k+1].z * x1.z + wr[2*k+1].w * x1.w;
        }

        // sq_norm over 16 o: 4 local squares + 2-step DPP butterfly across the 4-lane group
        float sq = u[0]*u[0] + u[1]*u[1] + u[2]*u[2] + u[3]*u[3];
        sq += dpp_quad<0xB1>(sq);     // quad_perm [1,0,3,2] : xor 1
        sq += dpp_quad<0x4E>(sq);     // quad_perm [2,3,0,1] : xor 2

        // factor = sq / ((1+sq) * sqrt(sq+1e-9)) via fast rcp/rsq
        const float f = sq * __builtin_amdgcn_rcpf(1.0f + sq)
                           * __builtin_amdgcn_rsqf(sq + 1e-9f);

        f32x4 v;
        v.x = u[0] * f; v.y = u[1] * f; v.z = u[2] * f; v.w = u[3] * f;
        *op = v;                              // plain cached store (L2 write-combining)
        op += (NC * NR * NO) / 4;             // next b
    }
}

extern "C" void kernel_launch(void* const* d_in, const int* in_sizes, int n_in,
                              void* d_out, int out_size, void* d_ws, size_t ws_size,
                              hipStream_t stream) {
    const float* x = (const float*)d_in[0];   // [256, 1152, 8]
    const float* W = (const float*)d_in[1];   // [1, 10, 1152, 16, 8]
    float* out = (float*)d_out;               // [256, 10, 1152, 16]

    dim3 grid(NC * NR / WPB, NB / BPB);       // (180, 16)
    dim3 block(256);
    capsule_squash_kernel<<<grid, block, 0, stream>>>(x, W, out);
}

// Round 8
// 38.929 us; speedup vs baseline: 1.1626x; 1.1626x over previous
//
#include <hip/hip_runtime.h>

// CapsuleLayer: u_hat[b,c,r,o] = sum_i W[c,r,o,i] * x[b,r,i]; out = squash(u_hat) over o.
// B=256, C=10, R=1152, I=8, O=16. fp32. Roofline: 188.7 MB NT write + reads ≈ 30-32 us.
//
// R8 = R5 (best, 39.3 us: LDS-staged x, NT dwordx4 stores, 2880 blocks) + ONE change:
// XCD-aware block swizzle. The 10 blocks (c=0..9) sharing one x-slice [16b x 64r] are
// placed consecutively on the SAME XCD (dispatch round-robins n%8), so x is fetched into
// that XCD's L2 once and hit 9 times, instead of 10 XCDs each refetching from L3.
// Bijective decode: n = (q%8) + 8*(c + 10*(q/8)), q = rblk + 18*by.

#define NB 256
#define NC 10
#define NR 1152
#define NI 8
#define NO 16
#define BPB 16            // batches per block
#define WPB 64            // (c,r) pairs per block

typedef float f32x4 __attribute__((ext_vector_type(4)));

template <int CTRL>
__device__ __forceinline__ float dpp_quad(float v) {
    int i = __builtin_bit_cast(int, v);
    int r = __builtin_amdgcn_update_dpp(i, i, CTRL, 0xF, 0xF, true);
    return __builtin_bit_cast(float, r);
}

__global__ __launch_bounds__(256, 5) void capsule_squash_kernel(
    const float* __restrict__ x,   // [B, R, I]
    const float* __restrict__ W,   // [C, R, O, I]
    float* __restrict__ out)       // [B, C, R, O]
{
    __shared__ float xs[BPB * WPB * NI];   // [16 b][64 r][8 i] = 32 KB

    // ---- XCD-aware decode of flat block id ----
    const int n    = blockIdx.x;       // 0..2879
    const int xcd  = n & 7;
    const int m    = n >> 3;
    const int c    = m % NC;           // 0..9  (the 10 sharers of one x-slice)
    const int qh   = m / NC;           // 0..35
    const int q    = qh * 8 + xcd;     // 0..287 = rblk + 18*by
    const int rblk = q % 18;
    const int by   = q / 18;           // 0..15

    const int w0 = c * NR + rblk * WPB;    // block's first w (64-aligned within c)
    const int r0 = rblk * WPB;
    const int b0 = by * BPB;

    const int tid = threadIdx.x;

    // ---- stage x[b0+0..15, r0+0..63, 0..7] -> LDS (8 dwordx4 per thread) ----
    {
        const int bi    = tid >> 4;        // b-slice 0..15
        const int chunk = tid & 15;        // float4 column 0..15
        const f32x4* src = reinterpret_cast<const f32x4*>(x + ((size_t)(b0 + bi) * NR + r0) * NI);
        f32x4* dst = reinterpret_cast<f32x4*>(xs + bi * (WPB * NI));
        #pragma unroll
        for (int k = 0; k < 8; ++k)
            dst[chunk + 16 * k] = src[chunk + 16 * k];
    }

    // ---- this lane's 4 W rows (8 float4 = 32 VGPR), overlapped with staging ----
    const int l4 = tid & 3;                // lane's o = l4*4 + 0..3
    const int g  = tid >> 2;               // group 0..63
    const int w  = w0 + g;
    const f32x4* wp = reinterpret_cast<const f32x4*>(W + (size_t)(w * NO + l4 * 4) * NI);
    f32x4 wr[8];
    #pragma unroll
    for (int k = 0; k < 8; ++k) wr[k] = wp[k];

    __syncthreads();

    f32x4* op = reinterpret_cast<f32x4*>(out + ((size_t)b0 * (NC * NR) + w) * NO + l4 * 4);
    const f32x4* xrow = reinterpret_cast<const f32x4*>(xs) + g * 2;

    #pragma unroll
    for (int j = 0; j < BPB; ++j) {
        const f32x4 x0 = xrow[j * (WPB * NI / 4)];
        const f32x4 x1 = xrow[j * (WPB * NI / 4) + 1];

        float u[4];
        #pragma unroll
        for (int k = 0; k < 4; ++k) {
            u[k] = wr[2*k].x   * x0.x + wr[2*k].y   * x0.y + wr[2*k].z   * x0.z + wr[2*k].w   * x0.w
                 + wr[2*k+1].x * x1.x + wr[2*k+1].y * x1.y + wr[2*k+1].z * x1.z + wr[2*k+1].w * x1.w;
        }

        // sq_norm over 16 o: 4 local squares + 2-step DPP butterfly across the 4-lane group
        float sq = u[0]*u[0] + u[1]*u[1] + u[2]*u[2] + u[3]*u[3];
        sq += dpp_quad<0xB1>(sq);     // quad_perm [1,0,3,2] : xor 1
        sq += dpp_quad<0x4E>(sq);     // quad_perm [2,3,0,1] : xor 2

        // factor = sq / ((1+sq) * sqrt(sq+1e-9)) via fast rcp/rsq
        const float f = sq * __builtin_amdgcn_rcpf(1.0f + sq)
                           * __builtin_amdgcn_rsqf(sq + 1e-9f);

        f32x4 v;
        v.x = u[0] * f; v.y = u[1] * f; v.z = u[2] * f; v.w = u[3] * f;
        __builtin_nontemporal_store(v, op);   // write-once stream: bypass L2 (proven +6us)
        op += (NC * NR * NO) / 4;             // next b
    }
}

extern "C" void kernel_launch(void* const* d_in, const int* in_sizes, int n_in,
                              void* d_out, int out_size, void* d_ws, size_t ws_size,
                              hipStream_t stream) {
    const float* x = (const float*)d_in[0];   // [256, 1152, 8]
    const float* W = (const float*)d_in[1];   // [1, 10, 1152, 16, 8]
    float* out = (float*)d_out;               // [256, 10, 1152, 16]

    dim3 grid(NC * NR / WPB * (NB / BPB));    // 2880 flat, XCD-decoded in-kernel
    dim3 block(256);
    capsule_squash_kernel<<<grid, block, 0, stream>>>(x, W, out);
}